// Round 7
// baseline (1382.231 us; speedup 1.0000x reference)
//
#include <hip/hip_runtime.h>

// CGLSTMEncoder via MFMA: 294912 seqs, T=120, H=32, D_IN=1.
// 16 seqs/batch, 8 mfma_f32_16x16x32_bf16 tiles/step (hi/lo bf16 split, 3
// MFMAs/tile => ~fp32). Transcendental-minimal elementwise (7 trans/elem).
// Round-12 change: BREAK THE PER-TILE MFMA DEPENDENCY CHAINS.
//   Evidence: r6 interleave moved VALUBusy only 71.6->75.4 (sum with
//   MfmaUtil still ~104%). VALU work/step ~= 1167 cyc/SIMD => floor
//   ~1050us at 100% issue; the missing 25% = both waves stalled at once.
//   Cause: every round issued each tile's 3 MFMAs as a DEPENDENT chain
//   (acc=mfma(ahi); acc=mfma(alo); acc=mfma(ahi,blo) back-to-back). A
//   wave's in-order issue stalls ~latency (16-32cy) between them, and the
//   queued VALU work behind can't issue either: ~16 bubbles x ~25cy =
//   the idle. Fix: 3 passes of 8 INDEPENDENT MFMAs (hh[0..7], lh[0..7],
//   hl[0..7]); same-tile dependents now >=40cy apart; per-acc accumulation
//   order unchanged => bit-identical numerics. Applied in fused_step and
//   gates8. Elementwise slices of the other batch remain interleaved.
//   * 2 batches/wave software pipeline (r11), 4 waves/WG, zero barriers.
//   * launch_bounds(256,2): proven no-spill (WRITE_SIZE==37MB sentinel).
// Gate order i,f,g,o: o is dead code in the reference and skipped.
// Layouts (verified): A: m=lane&15,k=quad*8+j; B: n=lane&15 holds W rows;
// C/D: col=lane&15, row=quad*4+reg.

#define NV 9
#define TLEN 120
#define HS 32
#define BATCH_ 32768
#define NSEQ (BATCH_ * NV)
#define NBATCH (NSEQ / 16)        // 18432 batches of 16 seqs
#define WPB 4                     // waves per block
#define GRID_ (NBATCH / (WPB * 2))// 2304 blocks, 2 batches per wave

#define TCHUNK 60            // timesteps staged per LDS refill (2 chunks)
#define XSTRIDE 20           // words per t-row of xT (16B-aligned quad reads)
#define HSTRIDE 36           // words per seq-row of hbuf

#define LOG2E 1.4426950408889634f
#define TWOL  2.8853900817779268f

typedef __attribute__((ext_vector_type(8))) short bf16x8;
typedef __attribute__((ext_vector_type(4))) float f32x4;
typedef __attribute__((ext_vector_type(4))) unsigned int u32x4;

__device__ __forceinline__ float fast_exp2(float x) { return __builtin_amdgcn_exp2f(x); }
__device__ __forceinline__ float fast_rcp(float x)  { return __builtin_amdgcn_rcpf(x); }
__device__ __forceinline__ unsigned int fbits(float x) { return __builtin_bit_cast(unsigned int, x); }
__device__ __forceinline__ float bcastf(unsigned int x) { return __builtin_bit_cast(float, x); }

__device__ __forceinline__ f32x4 splat4(float x) { f32x4 v = {x, x, x, x}; return v; }
__device__ __forceinline__ f32x4 fma4(f32x4 a, f32x4 b, f32x4 c) {
  return __builtin_elementwise_fma(a, b, c);
}
__device__ __forceinline__ f32x4 exp24(f32x4 v) {
  f32x4 r;
  r[0] = fast_exp2(v[0]); r[1] = fast_exp2(v[1]);
  r[2] = fast_exp2(v[2]); r[3] = fast_exp2(v[3]);
  return r;
}
__device__ __forceinline__ f32x4 rcp4(f32x4 v) {
  f32x4 r;
  r[0] = fast_rcp(v[0]); r[1] = fast_rcp(v[1]);
  r[2] = fast_rcp(v[2]); r[3] = fast_rcp(v[3]);
  return r;
}

// pack one h vector (4 rows) -> (bf16hi | bf16lo) words in hbuf
__device__ __forceinline__ void pack_h(unsigned int* __restrict__ hb, int base_col,
                                       int quad, const f32x4& h) {
#pragma unroll
  for (int r = 0; r < 4; ++r) {
    unsigned int hbits = fbits(h[r]);
    float lof = h[r] - bcastf(hbits & 0xffff0000u);
    hb[(quad * 4 + r) * HSTRIDE + base_col] =
        __builtin_amdgcn_perm(fbits(lof), hbits, 0x07060302u);
  }
}

// merged-LSTM elementwise for 4 seqs: inputs are PRESCALED pre-activations
// (ai,af,ac by -log2e; ag by -2log2e); ct is the scaled cell state.
__device__ __forceinline__ void lstm_elem(f32x4 ai, f32x4 af, f32x4 ag, f32x4 ac,
                                          f32x4& ct, f32x4& h) {
  const f32x4 one4 = splat4(1.0f);
  f32x4 Ei = exp24(ai), Ef = exp24(af), Eg = exp24(ag), Ea = exp24(ac);
  f32x4 pi_ = Ei + one4, pf_ = Ef + one4, pg_ = Eg + one4, pa_ = Ea + one4;
  f32x4 u   = fma4(Eg, splat4(TWOL), splat4(-TWOL));   // (-2L)*(1-Eg)
  f32x4 P   = pi_ * pg_;
  f32x4 tt  = pf_ * u;
  f32x4 num = fma4(ct, P, tt);
  f32x4 den = pf_ * P;
  ct = num * rcp4(den);
  f32x4 Ec  = exp24(ct);
  h = (one4 - Ec) * rcp4(pa_ * (Ec + one4));
}

// plain gates, 3 passes of 8 independent MFMAs -- prologue only
__device__ __forceinline__ void gates8(const unsigned int* __restrict__ hb,
                                       const float* __restrict__ xTw, int tl,
                                       int col, int quad,
                                       const bf16x8 (&bhi)[8], const bf16x8 (&blo)[8],
                                       const float (&wx)[8], const float (&bb)[8],
                                       f32x4 (&acc)[8]) {
  f32x4 xt4 = *(const f32x4*)&xTw[tl * XSTRIDE + quad * 4];
#pragma unroll
  for (int tile = 0; tile < 8; ++tile)
    acc[tile] = fma4(splat4(wx[tile]), xt4, splat4(bb[tile]));
  const unsigned int* hrow = &hb[col * HSTRIDE + quad * 8];
  u32x4 wa = *(const u32x4*)hrow;
  u32x4 wz = *(const u32x4*)(hrow + 4);
  u32x4 hi4, lo4;
  hi4[0] = __builtin_amdgcn_perm(wa[1], wa[0], 0x05040100u);
  hi4[1] = __builtin_amdgcn_perm(wa[3], wa[2], 0x05040100u);
  hi4[2] = __builtin_amdgcn_perm(wz[1], wz[0], 0x05040100u);
  hi4[3] = __builtin_amdgcn_perm(wz[3], wz[2], 0x05040100u);
  lo4[0] = __builtin_amdgcn_perm(wa[1], wa[0], 0x07060302u);
  lo4[1] = __builtin_amdgcn_perm(wa[3], wa[2], 0x07060302u);
  lo4[2] = __builtin_amdgcn_perm(wz[1], wz[0], 0x07060302u);
  lo4[3] = __builtin_amdgcn_perm(wz[3], wz[2], 0x07060302u);
  bf16x8 ahi = __builtin_bit_cast(bf16x8, hi4);
  bf16x8 alo = __builtin_bit_cast(bf16x8, lo4);
#pragma unroll
  for (int tile = 0; tile < 8; ++tile)
    acc[tile] = __builtin_amdgcn_mfma_f32_16x16x32_bf16(ahi, bhi[tile], acc[tile], 0, 0, 0);
#pragma unroll
  for (int tile = 0; tile < 8; ++tile)
    acc[tile] = __builtin_amdgcn_mfma_f32_16x16x32_bf16(alo, bhi[tile], acc[tile], 0, 0, 0);
#pragma unroll
  for (int tile = 0; tile < 8; ++tile)
    acc[tile] = __builtin_amdgcn_mfma_f32_16x16x32_bf16(ahi, blo[tile], acc[tile], 0, 0, 0);
}

// plain finish -- used only for the last B step of each chunk
__device__ __forceinline__ void finish8(unsigned int* __restrict__ hb, int col, int quad,
                                        f32x4 (&acc)[8],
                                        f32x4& ct0, f32x4& ct1, f32x4& h0, f32x4& h1) {
  lstm_elem(acc[0], acc[2], acc[4], acc[6], ct0, h0);
  lstm_elem(acc[1], acc[3], acc[5], acc[7], ct1, h1);
  pack_h(hb, col, quad, h0);
  pack_h(hb, col + 16, quad, h1);
}

#define MF_HH(T) accX[T] = __builtin_amdgcn_mfma_f32_16x16x32_bf16(ahi, bhi[T], accX[T], 0, 0, 0);
#define MF_LH(T) accX[T] = __builtin_amdgcn_mfma_f32_16x16x32_bf16(alo, bhi[T], accX[T], 0, 0, 0);
#define MF_HL(T) accX[T] = __builtin_amdgcn_mfma_f32_16x16x32_bf16(ahi, blo[T], accX[T], 0, 0, 0);

// Fused phase: batch-X gates (prep + 24 MFMAs in 3 independent passes)
// interleaved with batch-Y's elementwise finish. Within each pass the 8
// MFMAs are mutually independent; same-tile dependents are >=4 MFMAs +
// one VALU slice apart, so in-order issue never waits on MFMA latency.
__device__ __forceinline__ void fused_step(
    const unsigned int* __restrict__ hbX, const float* __restrict__ xTX, int tlX,
    f32x4 (&accX)[8],
    unsigned int* __restrict__ hbY, f32x4 (&accY)[8],
    f32x4& cY0, f32x4& cY1, f32x4& hY0, f32x4& hY1,
    int col, int quad,
    const bf16x8 (&bhi)[8], const bf16x8 (&blo)[8],
    const float (&wx)[8], const float (&bb)[8])
{
  const f32x4 one4 = splat4(1.0f);
  // ---- X prep: LDS reads + perms + acc init ----
  f32x4 xt4 = *(const f32x4*)&xTX[tlX * XSTRIDE + quad * 4];
#pragma unroll
  for (int t = 0; t < 8; ++t)
    accX[t] = fma4(splat4(wx[t]), xt4, splat4(bb[t]));
  const unsigned int* hrow = &hbX[col * HSTRIDE + quad * 8];
  u32x4 wa = *(const u32x4*)hrow;
  u32x4 wz = *(const u32x4*)(hrow + 4);
  u32x4 hi4, lo4;
  hi4[0] = __builtin_amdgcn_perm(wa[1], wa[0], 0x05040100u);
  hi4[1] = __builtin_amdgcn_perm(wa[3], wa[2], 0x05040100u);
  hi4[2] = __builtin_amdgcn_perm(wz[1], wz[0], 0x05040100u);
  hi4[3] = __builtin_amdgcn_perm(wz[3], wz[2], 0x05040100u);
  lo4[0] = __builtin_amdgcn_perm(wa[1], wa[0], 0x07060302u);
  lo4[1] = __builtin_amdgcn_perm(wa[3], wa[2], 0x07060302u);
  lo4[2] = __builtin_amdgcn_perm(wz[1], wz[0], 0x07060302u);
  lo4[3] = __builtin_amdgcn_perm(wz[3], wz[2], 0x07060302u);
  bf16x8 ahi = __builtin_bit_cast(bf16x8, hi4);
  bf16x8 alo = __builtin_bit_cast(bf16x8, lo4);

  // ---- pass HH (8 independent) with Y exp slices between half-passes ----
  MF_HH(0) MF_HH(1) MF_HH(2) MF_HH(3)
  f32x4 Ei0 = exp24(accY[0]);
  f32x4 Ef0 = exp24(accY[2]);
  MF_HH(4) MF_HH(5) MF_HH(6) MF_HH(7)
  f32x4 Eg0 = exp24(accY[4]);
  f32x4 Ea0 = exp24(accY[6]);
  // ---- pass LH ----
  MF_LH(0) MF_LH(1) MF_LH(2) MF_LH(3)
  f32x4 pi0 = Ei0 + one4, pf0 = Ef0 + one4, pg0 = Eg0 + one4, pa0 = Ea0 + one4;
  f32x4 u0   = fma4(Eg0, splat4(TWOL), splat4(-TWOL));
  f32x4 P0   = pi0 * pg0;
  f32x4 tt0  = pf0 * u0;
  f32x4 num0 = fma4(cY0, P0, tt0);
  f32x4 den0 = pf0 * P0;
  MF_LH(4) MF_LH(5) MF_LH(6) MF_LH(7)
  cY0 = num0 * rcp4(den0);
  f32x4 Ec0 = exp24(cY0);
  hY0 = (one4 - Ec0) * rcp4(pa0 * (Ec0 + one4));
  // ---- pass HL ----
  MF_HL(0) MF_HL(1) MF_HL(2) MF_HL(3)
  pack_h(hbY, col, quad, hY0);
  f32x4 Ei1 = exp24(accY[1]);
  f32x4 Ef1 = exp24(accY[3]);
  MF_HL(4) MF_HL(5) MF_HL(6) MF_HL(7)
  f32x4 Eg1 = exp24(accY[5]);
  f32x4 Ea1 = exp24(accY[7]);
  f32x4 pi1 = Ei1 + one4, pf1 = Ef1 + one4, pg1 = Eg1 + one4, pa1 = Ea1 + one4;
  f32x4 u1   = fma4(Eg1, splat4(TWOL), splat4(-TWOL));
  f32x4 P1   = pi1 * pg1;
  f32x4 tt1  = pf1 * u1;
  f32x4 num1 = fma4(cY1, P1, tt1);
  f32x4 den1 = pf1 * P1;
  cY1 = num1 * rcp4(den1);
  f32x4 Ec1 = exp24(cY1);
  hY1 = (one4 - Ec1) * rcp4(pa1 * (Ec1 + one4));
  pack_h(hbY, col + 16, quad, hY1);
}

__global__ __launch_bounds__(256, 2) void cglstm_kernel(
    const float* __restrict__ x,      // [B, NV*TLEN]
    const float* __restrict__ W_ih,   // [128, 1]
    const float* __restrict__ W_hh,   // [128, 32]
    const float* __restrict__ b_ih,   // [128]
    const float* __restrict__ b_hh,   // [128]
    const float* __restrict__ cg_w,   // [32, 1]
    const float* __restrict__ cg_u,   // [32, 32]
    const float* __restrict__ cg_b,   // [32]
    float* __restrict__ out)          // flat [s*HS + j]
{
  const int lane = threadIdx.x & 63;
  const int wid  = threadIdx.x >> 6;
  const int col  = lane & 15;
  const int quad = lane >> 4;

  // per-wave LDS slices (2 batches each); no cross-wave sharing, no barriers
  __shared__ __align__(16) float xT[WPB][2][TCHUNK * XSTRIDE];
  __shared__ __align__(16) unsigned int hbuf[WPB][2][16 * HSTRIDE];
  float* __restrict__ xTw0 = xT[wid][0];
  float* __restrict__ xTw1 = xT[wid][1];
  unsigned int* hb0 = hbuf[wid][0];
  unsigned int* hb1 = hbuf[wid][1];

  // ---- one-time: prescaled B fragments (W rows) as bf16 hi/lo ----
  bf16x8 bhi[8], blo[8];
  float wx[8], bb[8];
#pragma unroll
  for (int tile = 0; tile < 8; ++tile) {
    const int n = col + (tile & 1) * 16;
    const float sc_ = ((tile >> 1) == 2) ? -TWOL : -LOG2E;  // g gate: -2L
    const float* wrow = (tile < 6) ? (W_hh + (size_t)((tile >> 1) * HS + n) * HS)
                                   : (cg_u + (size_t)n * HS);
    bf16x8 vh, vl;
#pragma unroll
    for (int e = 0; e < 8; ++e) {
      float wv = wrow[quad * 8 + e] * sc_;
      unsigned int wbits = fbits(wv);
      float lo_f = wv - bcastf(wbits & 0xffff0000u);
      vh[e] = (short)(wbits >> 16);
      vl[e] = (short)(fbits(lo_f) >> 16);
    }
    bhi[tile] = vh; blo[tile] = vl;
    if (tile < 6) {
      const int gg = tile >> 1;
      wx[tile] = W_ih[gg * HS + n] * sc_;
      bb[tile] = (b_ih[gg * HS + n] + b_hh[gg * HS + n]) * sc_;
    } else {
      wx[tile] = cg_w[n] * sc_;
      bb[tile] = cg_b[n] * sc_;
    }
  }

  const int p0 = (blockIdx.x * WPB + wid) * 2;   // two adjacent batches/wave
  const int p1 = p0 + 1;
  const float4* xb0 = (const float4*)(x + (size_t)p0 * 16 * TLEN);
  const float4* xb1 = (const float4*)(x + (size_t)p1 * 16 * TLEN);

  for (int i = lane; i < 2 * 16 * HSTRIDE; i += 64) hb0[i] = 0u;  // hb0+hb1 contiguous
  f32x4 cA0 = splat4(0.f), cA1 = splat4(0.f), hA0 = splat4(0.f), hA1 = splat4(0.f);
  f32x4 cB0 = splat4(0.f), cB1 = splat4(0.f), hB0 = splat4(0.f), hB1 = splat4(0.f);
  f32x4 accA[8], accB[8];

#pragma unroll 1
  for (int chunk = 0; chunk < 2; ++chunk) {
    // ---- stage x^T for 60 timesteps per batch (240 float4 each) ----
    // each seq row is 30 float4; chunk offset = 15 float4
    for (int i = lane; i < 240; i += 64) {
      int s = i / 15;
      int j = i - s * 15;
      float4 v = xb0[s * 30 + chunk * 15 + j];
      int t0 = j * 4;
      xTw0[(t0 + 0) * XSTRIDE + s] = v.x;
      xTw0[(t0 + 1) * XSTRIDE + s] = v.y;
      xTw0[(t0 + 2) * XSTRIDE + s] = v.z;
      xTw0[(t0 + 3) * XSTRIDE + s] = v.w;
    }
    for (int i = lane; i < 240; i += 64) {
      int s = i / 15;
      int j = i - s * 15;
      float4 v = xb1[s * 30 + chunk * 15 + j];
      int t0 = j * 4;
      xTw1[(t0 + 0) * XSTRIDE + s] = v.x;
      xTw1[(t0 + 1) * XSTRIDE + s] = v.y;
      xTw1[(t0 + 2) * XSTRIDE + s] = v.z;
      xTw1[(t0 + 3) * XSTRIDE + s] = v.w;
    }
    // wave-internal LDS ordering: DS pipe is in-order per wave, no barrier

    // ---- software-pipelined loop ----
    gates8(hb0, xTw0, 0, col, quad, bhi, blo, wx, bb, accA);   // prologue A(0)
#pragma unroll 1
    for (int tl = 0; tl < TCHUNK - 1; ++tl) {
      // B(tl) MFMAs interleaved with A(tl) finish (writes hb0 for tl+1)
      fused_step(hb1, xTw1, tl, accB, hb0, accA, cA0, cA1, hA0, hA1,
                 col, quad, bhi, blo, wx, bb);
      // A(tl+1) MFMAs interleaved with B(tl) finish (writes hb1 for tl+1)
      fused_step(hb0, xTw0, tl + 1, accA, hb1, accB, cB0, cB1, hB0, hB1,
                 col, quad, bhi, blo, wx, bb);
    }
    // tail: B(59) MFMAs + A(59) finish, then plain B(59) finish
    fused_step(hb1, xTw1, TCHUNK - 1, accB, hb0, accA, cA0, cA1, hA0, hA1,
               col, quad, bhi, blo, wx, bb);
    finish8(hb1, col, quad, accB, cB0, cB1, hB0, hB1);
  }

  // ---- epilogue ----
  float* ob0 = out + (size_t)p0 * 16 * HS;
  float* ob1 = out + (size_t)p1 * 16 * HS;
#pragma unroll
  for (int r = 0; r < 4; ++r) {
    ob0[(quad * 4 + r) * HS + col]      = hA0[r];
    ob0[(quad * 4 + r) * HS + col + 16] = hA1[r];
    ob1[(quad * 4 + r) * HS + col]      = hB0[r];
    ob1[(quad * 4 + r) * HS + col + 16] = hB1[r];
  }
}

extern "C" void kernel_launch(void* const* d_in, const int* in_sizes, int n_in,
                              void* d_out, int out_size, void* d_ws, size_t ws_size,
                              hipStream_t stream) {
  const float* x    = (const float*)d_in[0];
  const float* W_ih = (const float*)d_in[1];
  const float* W_hh = (const float*)d_in[2];
  const float* b_ih = (const float*)d_in[3];
  const float* b_hh = (const float*)d_in[4];
  const float* cg_w = (const float*)d_in[5];
  const float* cg_u = (const float*)d_in[6];
  const float* cg_b = (const float*)d_in[7];
  float* out = (float*)d_out;

  dim3 grid(GRID_), block(256);
  hipLaunchKernelGGL(cglstm_kernel, grid, block, 0, stream,
                     x, W_ih, W_hh, b_ih, b_hh, cg_w, cg_u, cg_b, out);
}

// Round 8
// 1375.431 us; speedup vs baseline: 1.0049x; 1.0049x over previous
//
#include <hip/hip_runtime.h>

// CGLSTMEncoder via MFMA: 294912 seqs, T=120, H=32, D_IN=1.
// 16 seqs/batch, 8 mfma_f32_16x16x32_bf16 tiles/step (hi/lo bf16 split, 3
// MFMAs/tile => ~fp32). Transcendental-minimal elementwise (7 trans/elem).
// Round-13 change: ROTATE PHASE ORDER to hide the LDS turnarounds.
//   Evidence: r6 interleave +4%, r7 chain-break 0% -- VALUBusy stuck at 75,
//   Mfma 28, sum ~103%. The stall the compiler CANNOT fix: each phase ends
//   with pack_h writes to hbY and the next phase immediately reads hbY
//   (RAW, no hoist possible) and consumes xt4/hrow right after issuing
//   them -- two exposed ~120cy DS latencies per phase ~= the 25% idle.
//   New phase order: [issue X reads][ENTIRE Y finish ~500cy][perms +
//   acc-init + 24 MFMAs ~190cy]. Next phase's hbY read now sits ~190cy
//   after the pack writes; xt4/wa/wz are consumed ~500cy after issue.
//   Bit-identical math; only placement changed. r6's intra-MFMA VALU
//   slices dropped (no intra-wave MFMA waits remain; TLP covers issue).
//   * 2 batches/wave pipeline, 4 waves/WG, zero barriers, (256,2) budget.
// Gate order i,f,g,o: o is dead code in the reference and skipped.
// Layouts (verified): A: m=lane&15,k=quad*8+j; B: n=lane&15 holds W rows;
// C/D: col=lane&15, row=quad*4+reg.

#define NV 9
#define TLEN 120
#define HS 32
#define BATCH_ 32768
#define NSEQ (BATCH_ * NV)
#define NBATCH (NSEQ / 16)        // 18432 batches of 16 seqs
#define WPB 4                     // waves per block
#define GRID_ (NBATCH / (WPB * 2))// 2304 blocks, 2 batches per wave

#define TCHUNK 60            // timesteps staged per LDS refill (2 chunks)
#define XSTRIDE 20           // words per t-row of xT (16B-aligned quad reads)
#define HSTRIDE 36           // words per seq-row of hbuf

#define LOG2E 1.4426950408889634f
#define TWOL  2.8853900817779268f

typedef __attribute__((ext_vector_type(8))) short bf16x8;
typedef __attribute__((ext_vector_type(4))) float f32x4;
typedef __attribute__((ext_vector_type(4))) unsigned int u32x4;

__device__ __forceinline__ float fast_exp2(float x) { return __builtin_amdgcn_exp2f(x); }
__device__ __forceinline__ float fast_rcp(float x)  { return __builtin_amdgcn_rcpf(x); }
__device__ __forceinline__ unsigned int fbits(float x) { return __builtin_bit_cast(unsigned int, x); }
__device__ __forceinline__ float bcastf(unsigned int x) { return __builtin_bit_cast(float, x); }

__device__ __forceinline__ f32x4 splat4(float x) { f32x4 v = {x, x, x, x}; return v; }
__device__ __forceinline__ f32x4 fma4(f32x4 a, f32x4 b, f32x4 c) {
  return __builtin_elementwise_fma(a, b, c);
}
__device__ __forceinline__ f32x4 exp24(f32x4 v) {
  f32x4 r;
  r[0] = fast_exp2(v[0]); r[1] = fast_exp2(v[1]);
  r[2] = fast_exp2(v[2]); r[3] = fast_exp2(v[3]);
  return r;
}
__device__ __forceinline__ f32x4 rcp4(f32x4 v) {
  f32x4 r;
  r[0] = fast_rcp(v[0]); r[1] = fast_rcp(v[1]);
  r[2] = fast_rcp(v[2]); r[3] = fast_rcp(v[3]);
  return r;
}

// pack one h vector (4 rows) -> (bf16hi | bf16lo) words in hbuf
__device__ __forceinline__ void pack_h(unsigned int* __restrict__ hb, int base_col,
                                       int quad, const f32x4& h) {
#pragma unroll
  for (int r = 0; r < 4; ++r) {
    unsigned int hbits = fbits(h[r]);
    float lof = h[r] - bcastf(hbits & 0xffff0000u);
    hb[(quad * 4 + r) * HSTRIDE + base_col] =
        __builtin_amdgcn_perm(fbits(lof), hbits, 0x07060302u);
  }
}

// merged-LSTM elementwise for 4 seqs: inputs are PRESCALED pre-activations
// (ai,af,ac by -log2e; ag by -2log2e); ct is the scaled cell state.
__device__ __forceinline__ void lstm_elem(f32x4 ai, f32x4 af, f32x4 ag, f32x4 ac,
                                          f32x4& ct, f32x4& h) {
  const f32x4 one4 = splat4(1.0f);
  f32x4 Ei = exp24(ai), Ef = exp24(af), Eg = exp24(ag), Ea = exp24(ac);
  f32x4 pi_ = Ei + one4, pf_ = Ef + one4, pg_ = Eg + one4, pa_ = Ea + one4;
  f32x4 u   = fma4(Eg, splat4(TWOL), splat4(-TWOL));   // (-2L)*(1-Eg)
  f32x4 P   = pi_ * pg_;
  f32x4 tt  = pf_ * u;
  f32x4 num = fma4(ct, P, tt);
  f32x4 den = pf_ * P;
  ct = num * rcp4(den);
  f32x4 Ec  = exp24(ct);
  h = (one4 - Ec) * rcp4(pa_ * (Ec + one4));
}

// plain gates, 3 passes of 8 independent MFMAs -- prologue only
__device__ __forceinline__ void gates8(const unsigned int* __restrict__ hb,
                                       const float* __restrict__ xTw, int tl,
                                       int col, int quad,
                                       const bf16x8 (&bhi)[8], const bf16x8 (&blo)[8],
                                       const float (&wx)[8], const float (&bb)[8],
                                       f32x4 (&acc)[8]) {
  f32x4 xt4 = *(const f32x4*)&xTw[tl * XSTRIDE + quad * 4];
#pragma unroll
  for (int tile = 0; tile < 8; ++tile)
    acc[tile] = fma4(splat4(wx[tile]), xt4, splat4(bb[tile]));
  const unsigned int* hrow = &hb[col * HSTRIDE + quad * 8];
  u32x4 wa = *(const u32x4*)hrow;
  u32x4 wz = *(const u32x4*)(hrow + 4);
  u32x4 hi4, lo4;
  hi4[0] = __builtin_amdgcn_perm(wa[1], wa[0], 0x05040100u);
  hi4[1] = __builtin_amdgcn_perm(wa[3], wa[2], 0x05040100u);
  hi4[2] = __builtin_amdgcn_perm(wz[1], wz[0], 0x05040100u);
  hi4[3] = __builtin_amdgcn_perm(wz[3], wz[2], 0x05040100u);
  lo4[0] = __builtin_amdgcn_perm(wa[1], wa[0], 0x07060302u);
  lo4[1] = __builtin_amdgcn_perm(wa[3], wa[2], 0x07060302u);
  lo4[2] = __builtin_amdgcn_perm(wz[1], wz[0], 0x07060302u);
  lo4[3] = __builtin_amdgcn_perm(wz[3], wz[2], 0x07060302u);
  bf16x8 ahi = __builtin_bit_cast(bf16x8, hi4);
  bf16x8 alo = __builtin_bit_cast(bf16x8, lo4);
#pragma unroll
  for (int tile = 0; tile < 8; ++tile)
    acc[tile] = __builtin_amdgcn_mfma_f32_16x16x32_bf16(ahi, bhi[tile], acc[tile], 0, 0, 0);
#pragma unroll
  for (int tile = 0; tile < 8; ++tile)
    acc[tile] = __builtin_amdgcn_mfma_f32_16x16x32_bf16(alo, bhi[tile], acc[tile], 0, 0, 0);
#pragma unroll
  for (int tile = 0; tile < 8; ++tile)
    acc[tile] = __builtin_amdgcn_mfma_f32_16x16x32_bf16(ahi, blo[tile], acc[tile], 0, 0, 0);
}

// plain finish -- used only for the last B step of each chunk
__device__ __forceinline__ void finish8(unsigned int* __restrict__ hb, int col, int quad,
                                        f32x4 (&acc)[8],
                                        f32x4& ct0, f32x4& ct1, f32x4& h0, f32x4& h1) {
  lstm_elem(acc[0], acc[2], acc[4], acc[6], ct0, h0);
  lstm_elem(acc[1], acc[3], acc[5], acc[7], ct1, h1);
  pack_h(hb, col, quad, h0);
  pack_h(hb, col + 16, quad, h1);
}

// Rotated fused phase:
//   (1) issue X operand reads (xt4, h-frag words)      -- DS latency ->
//   (2) ENTIRE Y finish (trans chain + pack_h -> hbY)  -- ~500cy cover
//   (3) perms + acc-init + 24 MFMAs (3 indep passes)   -- ~190cy cover
// so the NEXT phase's hbY read sits ~190cy after Y's pack writes, and
// xt4/wa/wz are consumed ~500cy after issue. No exposed DS latency.
__device__ __forceinline__ void fused_step(
    const unsigned int* __restrict__ hbX, const float* __restrict__ xTX, int tlX,
    f32x4 (&accX)[8],
    unsigned int* __restrict__ hbY, f32x4 (&accY)[8],
    f32x4& cY0, f32x4& cY1, f32x4& hY0, f32x4& hY1,
    int col, int quad,
    const bf16x8 (&bhi)[8], const bf16x8 (&blo)[8],
    const float (&wx)[8], const float (&bb)[8])
{
  // ---- (1) issue X reads ----
  f32x4 xt4 = *(const f32x4*)&xTX[tlX * XSTRIDE + quad * 4];
  const unsigned int* hrow = &hbX[col * HSTRIDE + quad * 8];
  u32x4 wa = *(const u32x4*)hrow;
  u32x4 wz = *(const u32x4*)(hrow + 4);

  // ---- (2) entire Y finish ----
  lstm_elem(accY[0], accY[2], accY[4], accY[6], cY0, hY0);
  pack_h(hbY, col, quad, hY0);
  lstm_elem(accY[1], accY[3], accY[5], accY[7], cY1, hY1);
  pack_h(hbY, col + 16, quad, hY1);

  // ---- (3) perms + acc-init + MFMAs ----
  u32x4 hi4, lo4;
  hi4[0] = __builtin_amdgcn_perm(wa[1], wa[0], 0x05040100u);
  hi4[1] = __builtin_amdgcn_perm(wa[3], wa[2], 0x05040100u);
  hi4[2] = __builtin_amdgcn_perm(wz[1], wz[0], 0x05040100u);
  hi4[3] = __builtin_amdgcn_perm(wz[3], wz[2], 0x05040100u);
  lo4[0] = __builtin_amdgcn_perm(wa[1], wa[0], 0x07060302u);
  lo4[1] = __builtin_amdgcn_perm(wa[3], wa[2], 0x07060302u);
  lo4[2] = __builtin_amdgcn_perm(wz[1], wz[0], 0x07060302u);
  lo4[3] = __builtin_amdgcn_perm(wz[3], wz[2], 0x07060302u);
  bf16x8 ahi = __builtin_bit_cast(bf16x8, hi4);
  bf16x8 alo = __builtin_bit_cast(bf16x8, lo4);
#pragma unroll
  for (int t = 0; t < 8; ++t)
    accX[t] = fma4(splat4(wx[t]), xt4, splat4(bb[t]));
#pragma unroll
  for (int t = 0; t < 8; ++t)
    accX[t] = __builtin_amdgcn_mfma_f32_16x16x32_bf16(ahi, bhi[t], accX[t], 0, 0, 0);
#pragma unroll
  for (int t = 0; t < 8; ++t)
    accX[t] = __builtin_amdgcn_mfma_f32_16x16x32_bf16(alo, bhi[t], accX[t], 0, 0, 0);
#pragma unroll
  for (int t = 0; t < 8; ++t)
    accX[t] = __builtin_amdgcn_mfma_f32_16x16x32_bf16(ahi, blo[t], accX[t], 0, 0, 0);
}

__global__ __launch_bounds__(256, 2) void cglstm_kernel(
    const float* __restrict__ x,      // [B, NV*TLEN]
    const float* __restrict__ W_ih,   // [128, 1]
    const float* __restrict__ W_hh,   // [128, 32]
    const float* __restrict__ b_ih,   // [128]
    const float* __restrict__ b_hh,   // [128]
    const float* __restrict__ cg_w,   // [32, 1]
    const float* __restrict__ cg_u,   // [32, 32]
    const float* __restrict__ cg_b,   // [32]
    float* __restrict__ out)          // flat [s*HS + j]
{
  const int lane = threadIdx.x & 63;
  const int wid  = threadIdx.x >> 6;
  const int col  = lane & 15;
  const int quad = lane >> 4;

  // per-wave LDS slices (2 batches each); no cross-wave sharing, no barriers
  __shared__ __align__(16) float xT[WPB][2][TCHUNK * XSTRIDE];
  __shared__ __align__(16) unsigned int hbuf[WPB][2][16 * HSTRIDE];
  float* __restrict__ xTw0 = xT[wid][0];
  float* __restrict__ xTw1 = xT[wid][1];
  unsigned int* hb0 = hbuf[wid][0];
  unsigned int* hb1 = hbuf[wid][1];

  // ---- one-time: prescaled B fragments (W rows) as bf16 hi/lo ----
  bf16x8 bhi[8], blo[8];
  float wx[8], bb[8];
#pragma unroll
  for (int tile = 0; tile < 8; ++tile) {
    const int n = col + (tile & 1) * 16;
    const float sc_ = ((tile >> 1) == 2) ? -TWOL : -LOG2E;  // g gate: -2L
    const float* wrow = (tile < 6) ? (W_hh + (size_t)((tile >> 1) * HS + n) * HS)
                                   : (cg_u + (size_t)n * HS);
    bf16x8 vh, vl;
#pragma unroll
    for (int e = 0; e < 8; ++e) {
      float wv = wrow[quad * 8 + e] * sc_;
      unsigned int wbits = fbits(wv);
      float lo_f = wv - bcastf(wbits & 0xffff0000u);
      vh[e] = (short)(wbits >> 16);
      vl[e] = (short)(fbits(lo_f) >> 16);
    }
    bhi[tile] = vh; blo[tile] = vl;
    if (tile < 6) {
      const int gg = tile >> 1;
      wx[tile] = W_ih[gg * HS + n] * sc_;
      bb[tile] = (b_ih[gg * HS + n] + b_hh[gg * HS + n]) * sc_;
    } else {
      wx[tile] = cg_w[n] * sc_;
      bb[tile] = cg_b[n] * sc_;
    }
  }

  const int p0 = (blockIdx.x * WPB + wid) * 2;   // two adjacent batches/wave
  const int p1 = p0 + 1;
  const float4* xb0 = (const float4*)(x + (size_t)p0 * 16 * TLEN);
  const float4* xb1 = (const float4*)(x + (size_t)p1 * 16 * TLEN);

  for (int i = lane; i < 2 * 16 * HSTRIDE; i += 64) hb0[i] = 0u;  // hb0+hb1 contiguous
  f32x4 cA0 = splat4(0.f), cA1 = splat4(0.f), hA0 = splat4(0.f), hA1 = splat4(0.f);
  f32x4 cB0 = splat4(0.f), cB1 = splat4(0.f), hB0 = splat4(0.f), hB1 = splat4(0.f);
  f32x4 accA[8], accB[8];

#pragma unroll 1
  for (int chunk = 0; chunk < 2; ++chunk) {
    // ---- stage x^T for 60 timesteps per batch (240 float4 each) ----
    // each seq row is 30 float4; chunk offset = 15 float4
    for (int i = lane; i < 240; i += 64) {
      int s = i / 15;
      int j = i - s * 15;
      float4 v = xb0[s * 30 + chunk * 15 + j];
      int t0 = j * 4;
      xTw0[(t0 + 0) * XSTRIDE + s] = v.x;
      xTw0[(t0 + 1) * XSTRIDE + s] = v.y;
      xTw0[(t0 + 2) * XSTRIDE + s] = v.z;
      xTw0[(t0 + 3) * XSTRIDE + s] = v.w;
    }
    for (int i = lane; i < 240; i += 64) {
      int s = i / 15;
      int j = i - s * 15;
      float4 v = xb1[s * 30 + chunk * 15 + j];
      int t0 = j * 4;
      xTw1[(t0 + 0) * XSTRIDE + s] = v.x;
      xTw1[(t0 + 1) * XSTRIDE + s] = v.y;
      xTw1[(t0 + 2) * XSTRIDE + s] = v.z;
      xTw1[(t0 + 3) * XSTRIDE + s] = v.w;
    }
    // wave-internal LDS ordering: DS pipe is in-order per wave, no barrier

    // ---- software-pipelined loop ----
    gates8(hb0, xTw0, 0, col, quad, bhi, blo, wx, bb, accA);   // prologue A(0)
#pragma unroll 1
    for (int tl = 0; tl < TCHUNK - 1; ++tl) {
      // B(tl) gates (reads hb1) after A(tl) finish (writes hb0)
      fused_step(hb1, xTw1, tl, accB, hb0, accA, cA0, cA1, hA0, hA1,
                 col, quad, bhi, blo, wx, bb);
      // A(tl+1) gates (reads hb0, ~190cy after its writes) after B finish
      fused_step(hb0, xTw0, tl + 1, accA, hb1, accB, cB0, cB1, hB0, hB1,
                 col, quad, bhi, blo, wx, bb);
    }
    // tail: B(59) gates + A(59) finish, then plain B(59) finish
    fused_step(hb1, xTw1, TCHUNK - 1, accB, hb0, accA, cA0, cA1, hA0, hA1,
               col, quad, bhi, blo, wx, bb);
    finish8(hb1, col, quad, accB, cB0, cB1, hB0, hB1);
  }

  // ---- epilogue ----
  float* ob0 = out + (size_t)p0 * 16 * HS;
  float* ob1 = out + (size_t)p1 * 16 * HS;
#pragma unroll
  for (int r = 0; r < 4; ++r) {
    ob0[(quad * 4 + r) * HS + col]      = hA0[r];
    ob0[(quad * 4 + r) * HS + col + 16] = hA1[r];
    ob1[(quad * 4 + r) * HS + col]      = hB0[r];
    ob1[(quad * 4 + r) * HS + col + 16] = hB1[r];
  }
}

extern "C" void kernel_launch(void* const* d_in, const int* in_sizes, int n_in,
                              void* d_out, int out_size, void* d_ws, size_t ws_size,
                              hipStream_t stream) {
  const float* x    = (const float*)d_in[0];
  const float* W_ih = (const float*)d_in[1];
  const float* W_hh = (const float*)d_in[2];
  const float* b_ih = (const float*)d_in[3];
  const float* b_hh = (const float*)d_in[4];
  const float* cg_w = (const float*)d_in[5];
  const float* cg_u = (const float*)d_in[6];
  const float* cg_b = (const float*)d_in[7];
  float* out = (float*)d_out;

  dim3 grid(GRID_), block(256);
  hipLaunchKernelGGL(cglstm_kernel, grid, block, 0, stream,
                     x, W_ih, W_hh, b_ih, b_hh, cg_w, cg_u, cg_b, out);
}